// Round 1
// baseline (2447.254 us; speedup 1.0000x reference)
//
#include <hip/hip_runtime.h>
#include <math.h>

#define NROWS 8192
#define DDIM 384
#define HDIM 256
#define CDIM 6
#define NSPLIT 8
#define LN_EPS 1e-5f

// ---------------- helpers: top-16 list (sorted ascending by (d, j)) ----------------
__device__ __forceinline__ bool dj_better(float d1, int j1, float d2, int j2) {
    return (d1 < d2) || (d1 == d2 && j1 < j2);
}

__device__ __forceinline__ void topk_insert(float (&dv)[16], int (&ji)[16], float d, int j) {
    if (dj_better(d, j, dv[15], ji[15])) {
        dv[15] = d; ji[15] = j;
        #pragma unroll
        for (int t = 15; t > 0; --t) {
            bool m = dj_better(dv[t], ji[t], dv[t-1], ji[t-1]);
            float td = dv[t]; int tj = ji[t];
            dv[t]   = m ? dv[t-1] : dv[t];
            ji[t]   = m ? ji[t-1] : ji[t];
            dv[t-1] = m ? td : dv[t-1];
            ji[t-1] = m ? tj : ji[t-1];
        }
    }
}

// ---------------- Kernel A: sq[i] = ||x_i||^2, k[i] from tau ----------------
__global__ void __launch_bounds__(256) precompute_kernel(
    const float* __restrict__ x, const float* __restrict__ W_tau,
    const float* __restrict__ b_tau, float* __restrict__ sq, int* __restrict__ kk)
{
    int tid = threadIdx.x;
    int wave = tid >> 6, lane = tid & 63;
    int row = blockIdx.x * 4 + wave;
    const float* xr = x + (size_t)row * DDIM;
    float s = 0.f, tp = 0.f;
    #pragma unroll
    for (int q = 0; q < 6; ++q) {
        float v = xr[lane + 64 * q];
        s = fmaf(v, v, s);
        tp = fmaf(v, W_tau[lane + 64 * q], tp);
    }
    #pragma unroll
    for (int off = 32; off > 0; off >>= 1) {
        s += __shfl_xor(s, off);
        tp += __shfl_xor(tp, off);
    }
    if (lane == 0) {
        sq[row] = s;
        float u = tp + b_tau[0];
        float tau = 1.f / (1.f + expf(-u));
        float kf = rintf(16.f - 12.f * tau);   // round-half-even, matches jnp.round
        int k = (int)kf;
        k = min(16, max(1, k));
        kk[row] = k;
    }
}

// ---------------- fp32 tiled GEMM: out = relu(A[M,K] @ W[K,N] + bias) ----------------
// BM=BN=64, BK=16, 256 threads, 4x4 per thread
__global__ void __launch_bounds__(256) gemm_bias_relu_kernel(
    const float* __restrict__ A, const float* __restrict__ W,
    const float* __restrict__ bias, float* __restrict__ out,
    int N, int K)
{
    __shared__ __align__(16) float At[16][68];
    __shared__ __align__(16) float Bt[16][68];
    int tid = threadIdx.x;
    int ty = tid >> 4, tx = tid & 15;
    int rowbase = blockIdx.x * 64;
    int colbase = blockIdx.y * 64;
    int ar = tid >> 2, akq = tid & 3;           // A staging: row, k-quad
    int bk = tid >> 4, bnq = tid & 15;          // B staging: k, n-quad
    const float* Arow = A + (size_t)(rowbase + ar) * K + akq * 4;
    const float* Wp = W + (size_t)bk * N + colbase + bnq * 4;

    float acc[4][4] = {};
    for (int k0 = 0; k0 < K; k0 += 16) {
        float4 av = *(const float4*)(Arow + k0);
        float4 bv = *(const float4*)(Wp + (size_t)k0 * N);
        __syncthreads();
        At[akq*4+0][ar] = av.x; At[akq*4+1][ar] = av.y;
        At[akq*4+2][ar] = av.z; At[akq*4+3][ar] = av.w;
        *(float4*)&Bt[bk][bnq*4] = bv;
        __syncthreads();
        #pragma unroll
        for (int k = 0; k < 16; ++k) {
            float4 a4 = *(const float4*)&At[k][ty*4];
            float4 b4 = *(const float4*)&Bt[k][tx*4];
            float a[4] = {a4.x, a4.y, a4.z, a4.w};
            float b[4] = {b4.x, b4.y, b4.z, b4.w};
            #pragma unroll
            for (int i = 0; i < 4; ++i)
                #pragma unroll
                for (int j = 0; j < 4; ++j)
                    acc[i][j] = fmaf(a[i], b[j], acc[i][j]);
        }
    }
    #pragma unroll
    for (int i = 0; i < 4; ++i) {
        int rr = rowbase + ty*4 + i;
        int cc = colbase + tx*4;
        float4 o;
        o.x = fmaxf(acc[i][0] + bias[cc+0], 0.f);
        o.y = fmaxf(acc[i][1] + bias[cc+1], 0.f);
        o.z = fmaxf(acc[i][2] + bias[cc+2], 0.f);
        o.w = fmaxf(acc[i][3] + bias[cc+3], 0.f);
        *(float4*)&out[(size_t)rr * N + cc] = o;
    }
}

// ---------------- Kernel C: fused fp32 distances + per-row running top-16 ----------------
// grid (128 rowblocks, NSPLIT col-splits); each block: 64 rows x 1024 cols
__global__ void __launch_bounds__(256) dist_topk_kernel(
    const float* __restrict__ x, const float* __restrict__ sq,
    float* __restrict__ pd, int* __restrict__ pj)
{
    __shared__ __align__(16) float At[16][68];
    __shared__ __align__(16) float Bt[16][68];
    __shared__ __align__(16) float Dt[64][68];
    int tid = threadIdx.x;
    int ty = tid >> 4, tx = tid & 15;
    int rowbase = blockIdx.x * 64;
    int split = blockIdx.y;
    int ar = tid >> 2, akq = tid & 3;
    const float* Arow = x + (size_t)(rowbase + ar) * DDIM + akq * 4;

    // epilogue mapping: 4 threads per row
    int err = tid >> 2;       // row-in-block 0..63
    int eq  = tid & 3;        // col segment 0..3

    float dv[16]; int ji[16];
    #pragma unroll
    for (int t = 0; t < 16; ++t) { dv[t] = INFINITY; ji[t] = 0x7fffffff; }

    float sqr[4];
    #pragma unroll
    for (int i = 0; i < 4; ++i) sqr[i] = sq[rowbase + ty*4 + i];

    for (int ct = 0; ct < 1024/64; ++ct) {
        int colbase = split * 1024 + ct * 64;
        const float* Brow = x + (size_t)(colbase + ar) * DDIM + akq * 4;
        float acc[4][4] = {};
        for (int k0 = 0; k0 < DDIM; k0 += 16) {
            float4 av = *(const float4*)(Arow + k0);
            float4 bv = *(const float4*)(Brow + k0);
            __syncthreads();
            At[akq*4+0][ar] = av.x; At[akq*4+1][ar] = av.y;
            At[akq*4+2][ar] = av.z; At[akq*4+3][ar] = av.w;
            Bt[akq*4+0][ar] = bv.x; Bt[akq*4+1][ar] = bv.y;
            Bt[akq*4+2][ar] = bv.z; Bt[akq*4+3][ar] = bv.w;
            __syncthreads();
            #pragma unroll
            for (int k = 0; k < 16; ++k) {
                float4 a4 = *(const float4*)&At[k][ty*4];
                float4 b4 = *(const float4*)&Bt[k][tx*4];
                float a[4] = {a4.x, a4.y, a4.z, a4.w};
                float b[4] = {b4.x, b4.y, b4.z, b4.w};
                #pragma unroll
                for (int i = 0; i < 4; ++i)
                    #pragma unroll
                    for (int j = 0; j < 4; ++j)
                        acc[i][j] = fmaf(a[i], b[j], acc[i][j]);
            }
        }
        // d2 tile -> LDS (remap so each thread scans only its own row)
        float sqc[4];
        #pragma unroll
        for (int j = 0; j < 4; ++j) sqc[j] = sq[colbase + tx*4 + j];
        __syncthreads();
        #pragma unroll
        for (int i = 0; i < 4; ++i) {
            float4 o;
            o.x = sqr[i] + sqc[0] - 2.f * acc[i][0];
            o.y = sqr[i] + sqc[1] - 2.f * acc[i][1];
            o.z = sqr[i] + sqc[2] - 2.f * acc[i][2];
            o.w = sqr[i] + sqc[3] - 2.f * acc[i][3];
            *(float4*)&Dt[ty*4+i][tx*4] = o;
        }
        __syncthreads();
        #pragma unroll
        for (int c = 0; c < 16; ++c) {
            int col = eq * 16 + c;
            float d = Dt[err][col];
            int j = colbase + col;
            topk_insert(dv, ji, d, j);
        }
    }
    // merge the 4 lanes (tid = err*4+eq, partners within same wave)
    {
        float od[16]; int oj[16];
        #pragma unroll
        for (int t = 0; t < 16; ++t) { od[t] = __shfl_xor(dv[t], 1); oj[t] = __shfl_xor(ji[t], 1); }
        #pragma unroll
        for (int t = 0; t < 16; ++t) topk_insert(dv, ji, od[t], oj[t]);
        #pragma unroll
        for (int t = 0; t < 16; ++t) { od[t] = __shfl_xor(dv[t], 2); oj[t] = __shfl_xor(ji[t], 2); }
        #pragma unroll
        for (int t = 0; t < 16; ++t) topk_insert(dv, ji, od[t], oj[t]);
    }
    if (eq == 0) {
        int row = rowbase + err;
        size_t base = ((size_t)row * NSPLIT + split) * 16;
        #pragma unroll
        for (int t = 0; t < 16; ++t) { pd[base + t] = dv[t]; pj[base + t] = ji[t]; }
    }
}

// ---------------- merge splits -> final sorted idx[row][16] ----------------
__global__ void __launch_bounds__(256) topk_merge_kernel(
    const float* __restrict__ pd, const int* __restrict__ pj, int* __restrict__ idxOut)
{
    int row = blockIdx.x * 256 + threadIdx.x;
    float dv[16]; int ji[16];
    #pragma unroll
    for (int t = 0; t < 16; ++t) { dv[t] = INFINITY; ji[t] = 0x7fffffff; }
    for (int s = 0; s < NSPLIT; ++s) {
        size_t base = ((size_t)row * NSPLIT + s) * 16;
        #pragma unroll
        for (int t = 0; t < 16; ++t) topk_insert(dv, ji, pd[base + t], pj[base + t]);
    }
    #pragma unroll
    for (int t = 0; t < 16; ++t) idxOut[(size_t)row * 16 + t] = ji[t];
}

// ---------------- gather-mean: agg[row] = mean of first k neighbors' h ----------------
__global__ void __launch_bounds__(256) aggregate_kernel(
    const float* __restrict__ h, const int* __restrict__ idx, const int* __restrict__ kk,
    float* __restrict__ agg)
{
    int row = blockIdx.x, tid = threadIdx.x;
    __shared__ int sidx[16];
    __shared__ int sk;
    if (tid < 16) sidx[tid] = idx[(size_t)row * 16 + tid];
    if (tid == 0) sk = kk[row];
    __syncthreads();
    int k = sk;
    float acc = 0.f;
    for (int t = 0; t < k; ++t) acc += h[(size_t)sidx[t] * HDIM + tid];
    agg[(size_t)row * HDIM + tid] = acc / (float)k;
}

// ---------------- LayerNorm(h + r) * g + b, then @ W_fc + b_fc ----------------
__global__ void __launch_bounds__(256) ln_fc_kernel(
    const float* __restrict__ h, const float* __restrict__ r,
    const float* __restrict__ g, const float* __restrict__ bb,
    const float* __restrict__ W_fc, const float* __restrict__ b_fc,
    float* __restrict__ out)
{
    int row = blockIdx.x, tid = threadIdx.x;
    int wave = tid >> 6, lane = tid & 63;
    float z = h[(size_t)row * HDIM + tid] + r[(size_t)row * HDIM + tid];
    float s = z, s2 = z * z;
    #pragma unroll
    for (int off = 32; off > 0; off >>= 1) { s += __shfl_xor(s, off); s2 += __shfl_xor(s2, off); }
    __shared__ float red[8];
    __shared__ float smv[2];
    if (lane == 0) { red[wave] = s; red[4 + wave] = s2; }
    __syncthreads();
    if (tid == 0) {
        float ts = red[0] + red[1] + red[2] + red[3];
        float t2 = red[4] + red[5] + red[6] + red[7];
        float mu = ts / 256.f;
        float var = t2 / 256.f - mu * mu;
        smv[0] = mu; smv[1] = rsqrtf(var + LN_EPS);
    }
    __syncthreads();
    float zn = (z - smv[0]) * smv[1];
    float val = zn * g[tid] + bb[tid];
    float p[6];
    #pragma unroll
    for (int c = 0; c < 6; ++c) p[c] = val * W_fc[tid * 6 + c];
    #pragma unroll
    for (int c = 0; c < 6; ++c)
        #pragma unroll
        for (int off = 32; off > 0; off >>= 1) p[c] += __shfl_xor(p[c], off);
    __shared__ float pr[4][6];
    if (lane == 0) {
        #pragma unroll
        for (int c = 0; c < 6; ++c) pr[wave][c] = p[c];
    }
    __syncthreads();
    if (tid < 6)
        out[(size_t)row * CDIM + tid] = pr[0][tid] + pr[1][tid] + pr[2][tid] + pr[3][tid] + b_fc[tid];
}

extern "C" void kernel_launch(void* const* d_in, const int* in_sizes, int n_in,
                              void* d_out, int out_size, void* d_ws, size_t ws_size,
                              hipStream_t stream) {
    const float* x      = (const float*)d_in[0];
    const float* W_proj = (const float*)d_in[1];
    const float* b_proj = (const float*)d_in[2];
    const float* W_tau  = (const float*)d_in[3];
    const float* b_tau  = (const float*)d_in[4];
    const float* W_res  = (const float*)d_in[5];
    const float* b_res  = (const float*)d_in[6];
    const float* ln_g   = (const float*)d_in[7];
    const float* ln_b   = (const float*)d_in[8];
    const float* W_fc   = (const float*)d_in[9];
    const float* b_fc   = (const float*)d_in[10];
    float* out = (float*)d_out;

    char* ws = (char*)d_ws;
    float* sq  = (float*)ws;                         ws += (size_t)NROWS * 4;
    int*   kk  = (int*)ws;                           ws += (size_t)NROWS * 4;
    float* h   = (float*)ws;                         ws += (size_t)NROWS * HDIM * 4;
    float* agg = (float*)ws;                         ws += (size_t)NROWS * HDIM * 4;
    float* r   = (float*)ws;                         ws += (size_t)NROWS * HDIM * 4;
    float* pd  = (float*)ws;                         ws += (size_t)NROWS * NSPLIT * 16 * 4;
    int*   pj  = (int*)ws;                           ws += (size_t)NROWS * NSPLIT * 16 * 4;
    int*   idx = (int*)ws;                           ws += (size_t)NROWS * 16 * 4;

    precompute_kernel<<<NROWS / 4, 256, 0, stream>>>(x, W_tau, b_tau, sq, kk);
    gemm_bias_relu_kernel<<<dim3(NROWS / 64, HDIM / 64), 256, 0, stream>>>(
        x, W_proj, b_proj, h, HDIM, DDIM);
    dist_topk_kernel<<<dim3(NROWS / 64, NSPLIT), 256, 0, stream>>>(x, sq, pd, pj);
    topk_merge_kernel<<<NROWS / 256, 256, 0, stream>>>(pd, pj, idx);
    aggregate_kernel<<<NROWS, 256, 0, stream>>>(h, idx, kk, agg);
    gemm_bias_relu_kernel<<<dim3(NROWS / 64, HDIM / 64), 256, 0, stream>>>(
        agg, W_res, b_res, r, HDIM, HDIM);
    ln_fc_kernel<<<NROWS, 256, 0, stream>>>(h, r, ln_g, ln_b, W_fc, b_fc, out);
}

// Round 2
// 798.237 us; speedup vs baseline: 3.0658x; 3.0658x over previous
//
#include <hip/hip_runtime.h>
#include <math.h>

#define NROWS 8192
#define DDIM 384
#define HDIM 256
#define CDIM 6
#define NSPLIT 16
#define CHUNKS 4              // cols per split = CHUNKS*128 = 512
#define LN_EPS 1e-5f

typedef short bf16x8 __attribute__((ext_vector_type(8)));
typedef float f32x4 __attribute__((ext_vector_type(4)));

__device__ __forceinline__ bool dj_better(float d1, int j1, float d2, int j2) {
    return (d1 < d2) || (d1 == d2 && j1 < j2);
}

// float-only top-K insert (screening: tie-break unnecessary, see analysis)
template<int K>
__device__ __forceinline__ void topk_insert(float (&dv)[K], int (&ji)[K], float d, int j) {
    if (d < dv[K-1]) {
        dv[K-1] = d; ji[K-1] = j;
        #pragma unroll
        for (int t = K-1; t > 0; --t) {
            if (dv[t] < dv[t-1]) {
                float td = dv[t]; dv[t] = dv[t-1]; dv[t-1] = td;
                int tj = ji[t]; ji[t] = ji[t-1]; ji[t-1] = tj;
            }
        }
    }
}

// ---------------- x (fp32) -> bf16 bits, round-to-nearest-even ----------------
__global__ void __launch_bounds__(256) tobf16_kernel(
    const float* __restrict__ x, unsigned short* __restrict__ xb)
{
    int i = blockIdx.x * 256 + threadIdx.x;
    unsigned int u = __float_as_uint(x[i]);
    u += 0x7fffu + ((u >> 16) & 1u);
    xb[i] = (unsigned short)(u >> 16);
}

// ---------------- sq[i] = ||x_i||^2, k[i] from tau ----------------
__global__ void __launch_bounds__(256) precompute_kernel(
    const float* __restrict__ x, const float* __restrict__ W_tau,
    const float* __restrict__ b_tau, float* __restrict__ sq, int* __restrict__ kk)
{
    int tid = threadIdx.x;
    int wave = tid >> 6, lane = tid & 63;
    int row = blockIdx.x * 4 + wave;
    const float* xr = x + (size_t)row * DDIM;
    float s = 0.f, tp = 0.f;
    #pragma unroll
    for (int q = 0; q < 6; ++q) {
        float v = xr[lane + 64 * q];
        s = fmaf(v, v, s);
        tp = fmaf(v, W_tau[lane + 64 * q], tp);
    }
    #pragma unroll
    for (int off = 32; off > 0; off >>= 1) {
        s += __shfl_xor(s, off);
        tp += __shfl_xor(tp, off);
    }
    if (lane == 0) {
        sq[row] = s;
        float u = tp + b_tau[0];
        float tau = 1.f / (1.f + expf(-u));
        float kf = rintf(16.f - 12.f * tau);
        int k = (int)kf;
        k = min(16, max(1, k));
        kk[row] = k;
    }
}

// ---------------- fp32 tiled GEMM: out = relu(A[M,K] @ W[K,N] + bias) ----------------
__global__ void __launch_bounds__(256) gemm_bias_relu_kernel(
    const float* __restrict__ A, const float* __restrict__ W,
    const float* __restrict__ bias, float* __restrict__ out,
    int N, int K)
{
    __shared__ __align__(16) float At[16][68];
    __shared__ __align__(16) float Bt[16][68];
    int tid = threadIdx.x;
    int ty = tid >> 4, tx = tid & 15;
    int rowbase = blockIdx.x * 64;
    int colbase = blockIdx.y * 64;
    int ar = tid >> 2, akq = tid & 3;
    int bk = tid >> 4, bnq = tid & 15;
    const float* Arow = A + (size_t)(rowbase + ar) * K + akq * 4;
    const float* Wp = W + (size_t)bk * N + colbase + bnq * 4;

    float acc[4][4] = {};
    for (int k0 = 0; k0 < K; k0 += 16) {
        float4 av = *(const float4*)(Arow + k0);
        float4 bv = *(const float4*)(Wp + (size_t)k0 * N);
        __syncthreads();
        At[akq*4+0][ar] = av.x; At[akq*4+1][ar] = av.y;
        At[akq*4+2][ar] = av.z; At[akq*4+3][ar] = av.w;
        *(float4*)&Bt[bk][bnq*4] = bv;
        __syncthreads();
        #pragma unroll
        for (int k = 0; k < 16; ++k) {
            float4 a4 = *(const float4*)&At[k][ty*4];
            float4 b4 = *(const float4*)&Bt[k][tx*4];
            float a[4] = {a4.x, a4.y, a4.z, a4.w};
            float b[4] = {b4.x, b4.y, b4.z, b4.w};
            #pragma unroll
            for (int i = 0; i < 4; ++i)
                #pragma unroll
                for (int j = 0; j < 4; ++j)
                    acc[i][j] = fmaf(a[i], b[j], acc[i][j]);
        }
    }
    #pragma unroll
    for (int i = 0; i < 4; ++i) {
        int rr = rowbase + ty*4 + i;
        int cc = colbase + tx*4;
        float4 o;
        o.x = fmaxf(acc[i][0] + bias[cc+0], 0.f);
        o.y = fmaxf(acc[i][1] + bias[cc+1], 0.f);
        o.z = fmaxf(acc[i][2] + bias[cc+2], 0.f);
        o.w = fmaxf(acc[i][3] + bias[cc+3], 0.f);
        *(float4*)&out[(size_t)rr * N + cc] = o;
    }
}

// ---------------- MFMA bf16 Gram tiles + fused per-row top-16 screening ----------------
// grid (NROWS/128, NSPLIT), 256 threads (4 waves), 128x128 tile, K=384 in 12 steps of 32.
__global__ void __launch_bounds__(256) dist_topk_mfma_kernel(
    const unsigned short* __restrict__ xb, const float* __restrict__ sq,
    float* __restrict__ pd, int* __restrict__ pj)
{
    __shared__ unsigned short Abuf[128 * 32];   // 8 KB
    __shared__ unsigned short Bbuf[128 * 32];   // 8 KB
    __shared__ float Dt[128][65];               // 32.5 KB, stride 65 % 32 == 1 -> conflict-free scan

    const int tid = threadIdx.x;
    const int wave = tid >> 6;
    const int lane = tid & 63;
    const int rowbase = blockIdx.x * 128;
    const int split = blockIdx.y;
    const int wr = (wave >> 1) * 64;     // wave row offset in tile
    const int wc = (wave & 1) * 64;      // wave col offset in tile
    const int m16 = lane & 15;
    const int kq = lane >> 4;            // k-quad 0..3

    const int trow = tid >> 1;           // scan: 2 threads per row
    const int seg = tid & 1;

    const int er0 = tid >> 2;            // staging round 0: e = tid
    const int er1 = 64 + (tid >> 2);     // staging round 1: e = tid + 256
    const int eko = tid & 3;

    float dv[16]; int ji[16];
    #pragma unroll
    for (int t = 0; t < 16; ++t) { dv[t] = INFINITY; ji[t] = 0x7fffffff; }

    for (int chunk = 0; chunk < CHUNKS; ++chunk) {
        const int colbase = split * (CHUNKS * 128) + chunk * 128;
        f32x4 acc[4][4];
        #pragma unroll
        for (int a = 0; a < 4; ++a)
            #pragma unroll
            for (int b = 0; b < 4; ++b)
                acc[a][b] = (f32x4){0.f, 0.f, 0.f, 0.f};

        for (int kb = 0; kb < DDIM / 32; ++kb) {
            const int k0 = kb * 32;
            __syncthreads();
            // async global -> LDS staging, 16 B per lane, LDS dest = wave-uniform base + lane*16
            __builtin_amdgcn_global_load_lds(
                (const __attribute__((address_space(1))) void*)(xb + (size_t)(rowbase + er0) * DDIM + k0 + eko * 8),
                (__attribute__((address_space(3))) void*)((char*)Abuf + (wave * 64) * 16),
                16, 0, 0);
            __builtin_amdgcn_global_load_lds(
                (const __attribute__((address_space(1))) void*)(xb + (size_t)(rowbase + er1) * DDIM + k0 + eko * 8),
                (__attribute__((address_space(3))) void*)((char*)Abuf + (256 + wave * 64) * 16),
                16, 0, 0);
            __builtin_amdgcn_global_load_lds(
                (const __attribute__((address_space(1))) void*)(xb + (size_t)(colbase + er0) * DDIM + k0 + eko * 8),
                (__attribute__((address_space(3))) void*)((char*)Bbuf + (wave * 64) * 16),
                16, 0, 0);
            __builtin_amdgcn_global_load_lds(
                (const __attribute__((address_space(1))) void*)(xb + (size_t)(colbase + er1) * DDIM + k0 + eko * 8),
                (__attribute__((address_space(3))) void*)((char*)Bbuf + (256 + wave * 64) * 16),
                16, 0, 0);
            __syncthreads();

            bf16x8 af[4], bfr[4];
            #pragma unroll
            for (int s = 0; s < 4; ++s) {
                af[s]  = *(const bf16x8*)&Abuf[(wr + s * 16 + m16) * 32 + kq * 8];
                bfr[s] = *(const bf16x8*)&Bbuf[(wc + s * 16 + m16) * 32 + kq * 8];
            }
            #pragma unroll
            for (int si = 0; si < 4; ++si)
                #pragma unroll
                for (int sj = 0; sj < 4; ++sj)
                    acc[si][sj] = __builtin_amdgcn_mfma_f32_16x16x32_bf16(
                        af[si], bfr[sj], acc[si][sj], 0, 0, 0);
        }

        // epilogue: two column-halves through Dt (value = sq[col] - 2*dot; sq[row] is
        // row-constant and irrelevant for per-row ordering)
        float sqc[4];
        #pragma unroll
        for (int sj = 0; sj < 4; ++sj) sqc[sj] = sq[colbase + wc + sj * 16 + m16];

        #pragma unroll
        for (int h = 0; h < 2; ++h) {
            __syncthreads();
            #pragma unroll
            for (int si = 0; si < 4; ++si)
                #pragma unroll
                for (int sjh = 0; sjh < 2; ++sjh) {
                    int sj = h * 2 + sjh;
                    int sc = (wc >> 1) + sjh * 16 + m16;      // storage col 0..63
                    int r = wr + si * 16 + kq * 4;
                    #pragma unroll
                    for (int v = 0; v < 4; ++v)
                        Dt[r + v][sc] = sqc[sj] - 2.0f * acc[si][sj][v];
                }
            __syncthreads();
            // scan this half: storage cols seg*32 + c  <->  actual col seg*64 + h*32 + c
            #pragma unroll 4
            for (int c = 0; c < 32; ++c) {
                float d = Dt[trow][seg * 32 + c];
                topk_insert<16>(dv, ji, d, colbase + seg * 64 + h * 32 + c);
            }
        }
    }

    // merge the 2 segs of each row (partner lanes tid^1, same wave)
    {
        float od[16]; int oj[16];
        #pragma unroll
        for (int t = 0; t < 16; ++t) { od[t] = __shfl_xor(dv[t], 1); oj[t] = __shfl_xor(ji[t], 1); }
        #pragma unroll
        for (int t = 0; t < 16; ++t) topk_insert<16>(dv, ji, od[t], oj[t]);
    }
    if (seg == 0) {
        size_t base = ((size_t)(rowbase + trow) * NSPLIT + split) * 16;
        #pragma unroll
        for (int t = 0; t < 16; ++t) { pd[base + t] = dv[t]; pj[base + t] = ji[t]; }
    }
}

// ---------------- merge 16 split-lists -> approx top-32 candidates per row ----------------
__global__ void __launch_bounds__(256) topk_merge32_kernel(
    const float* __restrict__ pd, const int* __restrict__ pj, int* __restrict__ cand)
{
    int row = blockIdx.x * 256 + threadIdx.x;
    float dv[32]; int ji[32];
    #pragma unroll
    for (int t = 0; t < 32; ++t) { dv[t] = INFINITY; ji[t] = 0x7fffffff; }
    for (int s = 0; s < NSPLIT; ++s) {
        size_t base = ((size_t)row * NSPLIT + s) * 16;
        #pragma unroll
        for (int t = 0; t < 16; ++t)
            topk_insert<32>(dv, ji, pd[base + t], pj[base + t]);
    }
    #pragma unroll
    for (int t = 0; t < 32; ++t) cand[(size_t)row * 32 + t] = ji[t];
}

// ---------------- exact fp32 rescore of 32 candidates -> final sorted top-16 ----------------
// one wave per row; reference tie-break (smaller j on equal d)
__global__ void __launch_bounds__(256) rescore_kernel(
    const float* __restrict__ x, const float* __restrict__ sq,
    const int* __restrict__ cand, int* __restrict__ idxOut)
{
    int row = blockIdx.x * 4 + (threadIdx.x >> 6);
    int lane = threadIdx.x & 63;
    float xr[6];
    #pragma unroll
    for (int q = 0; q < 6; ++q) xr[q] = x[(size_t)row * DDIM + lane + 64 * q];
    int myj = cand[(size_t)row * 32 + (lane & 31)];
    float sqrow = sq[row];
    float myd = 0.f;
    for (int c = 0; c < 32; ++c) {
        int j = __shfl(myj, c);
        const float* xc = x + (size_t)j * DDIM;
        float p = 0.f;
        #pragma unroll
        for (int q = 0; q < 6; ++q) p = fmaf(xr[q], xc[lane + 64 * q], p);
        #pragma unroll
        for (int off = 32; off > 0; off >>= 1) p += __shfl_xor(p, off);
        float d = sqrow + sq[j] - 2.f * p;
        if (lane == c) myd = d;
    }
    int rank = 0;
    for (int t = 0; t < 32; ++t) {
        float dt = __shfl(myd, t); int jt = __shfl(myj, t);
        if (dj_better(dt, jt, myd, myj)) ++rank;
    }
    if (lane < 32 && rank < 16) idxOut[(size_t)row * 16 + rank] = myj;
}

// ---------------- gather-mean: agg[row] = mean of first k neighbors' h ----------------
__global__ void __launch_bounds__(256) aggregate_kernel(
    const float* __restrict__ h, const int* __restrict__ idx, const int* __restrict__ kk,
    float* __restrict__ agg)
{
    int row = blockIdx.x, tid = threadIdx.x;
    __shared__ int sidx[16];
    __shared__ int sk;
    if (tid < 16) sidx[tid] = idx[(size_t)row * 16 + tid];
    if (tid == 0) sk = kk[row];
    __syncthreads();
    int k = sk;
    float acc = 0.f;
    for (int t = 0; t < k; ++t) acc += h[(size_t)sidx[t] * HDIM + tid];
    agg[(size_t)row * HDIM + tid] = acc / (float)k;
}

// ---------------- LayerNorm(h + r) * g + b, then @ W_fc + b_fc ----------------
__global__ void __launch_bounds__(256) ln_fc_kernel(
    const float* __restrict__ h, const float* __restrict__ r,
    const float* __restrict__ g, const float* __restrict__ bb,
    const float* __restrict__ W_fc, const float* __restrict__ b_fc,
    float* __restrict__ out)
{
    int row = blockIdx.x, tid = threadIdx.x;
    int wave = tid >> 6, lane = tid & 63;
    float z = h[(size_t)row * HDIM + tid] + r[(size_t)row * HDIM + tid];
    float s = z, s2 = z * z;
    #pragma unroll
    for (int off = 32; off > 0; off >>= 1) { s += __shfl_xor(s, off); s2 += __shfl_xor(s2, off); }
    __shared__ float red[8];
    __shared__ float smv[2];
    if (lane == 0) { red[wave] = s; red[4 + wave] = s2; }
    __syncthreads();
    if (tid == 0) {
        float ts = red[0] + red[1] + red[2] + red[3];
        float t2 = red[4] + red[5] + red[6] + red[7];
        float mu = ts / 256.f;
        float var = t2 / 256.f - mu * mu;
        smv[0] = mu; smv[1] = rsqrtf(var + LN_EPS);
    }
    __syncthreads();
    float zn = (z - smv[0]) * smv[1];
    float val = zn * g[tid] + bb[tid];
    float p[6];
    #pragma unroll
    for (int c = 0; c < 6; ++c) p[c] = val * W_fc[tid * 6 + c];
    #pragma unroll
    for (int c = 0; c < 6; ++c)
        #pragma unroll
        for (int off = 32; off > 0; off >>= 1) p[c] += __shfl_xor(p[c], off);
    __shared__ float pr[4][6];
    if (lane == 0) {
        #pragma unroll
        for (int c = 0; c < 6; ++c) pr[wave][c] = p[c];
    }
    __syncthreads();
    if (tid < 6)
        out[(size_t)row * CDIM + tid] = pr[0][tid] + pr[1][tid] + pr[2][tid] + pr[3][tid] + b_fc[tid];
}

extern "C" void kernel_launch(void* const* d_in, const int* in_sizes, int n_in,
                              void* d_out, int out_size, void* d_ws, size_t ws_size,
                              hipStream_t stream) {
    const float* x      = (const float*)d_in[0];
    const float* W_proj = (const float*)d_in[1];
    const float* b_proj = (const float*)d_in[2];
    const float* W_tau  = (const float*)d_in[3];
    const float* b_tau  = (const float*)d_in[4];
    const float* W_res  = (const float*)d_in[5];
    const float* b_res  = (const float*)d_in[6];
    const float* ln_g   = (const float*)d_in[7];
    const float* ln_b   = (const float*)d_in[8];
    const float* W_fc   = (const float*)d_in[9];
    const float* b_fc   = (const float*)d_in[10];
    float* out = (float*)d_out;

    char* ws = (char*)d_ws;
    float* sq   = (float*)ws;                        ws += (size_t)NROWS * 4;
    int*   kk   = (int*)ws;                          ws += (size_t)NROWS * 4;
    float* h    = (float*)ws;                        ws += (size_t)NROWS * HDIM * 4;
    float* agg  = (float*)ws;                        ws += (size_t)NROWS * HDIM * 4;
    float* r    = (float*)ws;                        ws += (size_t)NROWS * HDIM * 4;
    float* pd   = (float*)ws;                        ws += (size_t)NROWS * NSPLIT * 16 * 4;
    int*   pj   = (int*)ws;                          ws += (size_t)NROWS * NSPLIT * 16 * 4;
    int*   idx  = (int*)ws;                          ws += (size_t)NROWS * 16 * 4;
    int*   cand = (int*)ws;                          ws += (size_t)NROWS * 32 * 4;
    unsigned short* xb = (unsigned short*)ws;        ws += (size_t)NROWS * DDIM * 2;

    tobf16_kernel<<<NROWS * DDIM / 256, 256, 0, stream>>>(x, xb);
    precompute_kernel<<<NROWS / 4, 256, 0, stream>>>(x, W_tau, b_tau, sq, kk);
    gemm_bias_relu_kernel<<<dim3(NROWS / 64, HDIM / 64), 256, 0, stream>>>(
        x, W_proj, b_proj, h, HDIM, DDIM);
    dist_topk_mfma_kernel<<<dim3(NROWS / 128, NSPLIT), 256, 0, stream>>>(xb, sq, pd, pj);
    topk_merge32_kernel<<<NROWS / 256, 256, 0, stream>>>(pd, pj, cand);
    rescore_kernel<<<NROWS / 4, 256, 0, stream>>>(x, sq, cand, idx);
    aggregate_kernel<<<NROWS, 256, 0, stream>>>(h, idx, kk, agg);
    gemm_bias_relu_kernel<<<dim3(NROWS / 64, HDIM / 64), 256, 0, stream>>>(
        agg, W_res, b_res, r, HDIM, HDIM);
    ln_fc_kernel<<<NROWS, 256, 0, stream>>>(h, r, ln_g, ln_b, W_fc, b_fc, out);
}

// Round 3
// 393.224 us; speedup vs baseline: 6.2236x; 2.0300x over previous
//
#include <hip/hip_runtime.h>
#include <hip/hip_fp16.h>
#include <math.h>

#define NROWS 8192
#define DDIM 384
#define HDIM 256
#define CDIM 6
#define LN_EPS 1e-5f

typedef short bf16x8 __attribute__((ext_vector_type(8)));
typedef float f32x4 __attribute__((ext_vector_type(4)));

__device__ __forceinline__ bool dj_better(float d1, int j1, float d2, int j2) {
    return (d1 < d2) || (d1 == d2 && j1 < j2);
}

// ---------------- x (fp32) -> bf16 bits, round-to-nearest-even ----------------
__global__ void __launch_bounds__(256) tobf16_kernel(
    const float* __restrict__ x, unsigned short* __restrict__ xb)
{
    int i = blockIdx.x * 256 + threadIdx.x;
    unsigned int u = __float_as_uint(x[i]);
    u += 0x7fffu + ((u >> 16) & 1u);
    xb[i] = (unsigned short)(u >> 16);
}

// ---------------- sq[i] = ||x_i||^2, k[i] from tau ----------------
__global__ void __launch_bounds__(256) precompute_kernel(
    const float* __restrict__ x, const float* __restrict__ W_tau,
    const float* __restrict__ b_tau, float* __restrict__ sq, int* __restrict__ kk)
{
    int tid = threadIdx.x;
    int wave = tid >> 6, lane = tid & 63;
    int row = blockIdx.x * 4 + wave;
    const float* xr = x + (size_t)row * DDIM;
    float s = 0.f, tp = 0.f;
    #pragma unroll
    for (int q = 0; q < 6; ++q) {
        float v = xr[lane + 64 * q];
        s = fmaf(v, v, s);
        tp = fmaf(v, W_tau[lane + 64 * q], tp);
    }
    #pragma unroll
    for (int off = 32; off > 0; off >>= 1) {
        s += __shfl_xor(s, off);
        tp += __shfl_xor(tp, off);
    }
    if (lane == 0) {
        sq[row] = s;
        float u = tp + b_tau[0];
        float tau = 1.f / (1.f + expf(-u));
        float kf = rintf(16.f - 12.f * tau);
        int k = (int)kf;
        k = min(16, max(1, k));
        kk[row] = k;
    }
}

// ---------------- fp32 tiled GEMM: out = relu(A[M,K] @ W[K,N] + bias) ----------------
__global__ void __launch_bounds__(256) gemm_bias_relu_kernel(
    const float* __restrict__ A, const float* __restrict__ W,
    const float* __restrict__ bias, float* __restrict__ out,
    int N, int K)
{
    __shared__ __align__(16) float At[16][68];
    __shared__ __align__(16) float Bt[16][68];
    int tid = threadIdx.x;
    int ty = tid >> 4, tx = tid & 15;
    int rowbase = blockIdx.x * 64;
    int colbase = blockIdx.y * 64;
    int ar = tid >> 2, akq = tid & 3;
    int bk = tid >> 4, bnq = tid & 15;
    const float* Arow = A + (size_t)(rowbase + ar) * K + akq * 4;
    const float* Wp = W + (size_t)bk * N + colbase + bnq * 4;

    float acc[4][4] = {};
    for (int k0 = 0; k0 < K; k0 += 16) {
        float4 av = *(const float4*)(Arow + k0);
        float4 bv = *(const float4*)(Wp + (size_t)k0 * N);
        __syncthreads();
        At[akq*4+0][ar] = av.x; At[akq*4+1][ar] = av.y;
        At[akq*4+2][ar] = av.z; At[akq*4+3][ar] = av.w;
        *(float4*)&Bt[bk][bnq*4] = bv;
        __syncthreads();
        #pragma unroll
        for (int k = 0; k < 16; ++k) {
            float4 a4 = *(const float4*)&At[k][ty*4];
            float4 b4 = *(const float4*)&Bt[k][tx*4];
            float a[4] = {a4.x, a4.y, a4.z, a4.w};
            float b[4] = {b4.x, b4.y, b4.z, b4.w};
            #pragma unroll
            for (int i = 0; i < 4; ++i)
                #pragma unroll
                for (int j = 0; j < 4; ++j)
                    acc[i][j] = fmaf(a[i], b[j], acc[i][j]);
        }
    }
    #pragma unroll
    for (int i = 0; i < 4; ++i) {
        int rr = rowbase + ty*4 + i;
        int cc = colbase + tx*4;
        float4 o;
        o.x = fmaxf(acc[i][0] + bias[cc+0], 0.f);
        o.y = fmaxf(acc[i][1] + bias[cc+1], 0.f);
        o.z = fmaxf(acc[i][2] + bias[cc+2], 0.f);
        o.w = fmaxf(acc[i][3] + bias[cc+3], 0.f);
        *(float4*)&out[(size_t)rr * N + cc] = o;
    }
}

// ---------------- pure MFMA bf16 Gram GEMM -> fp16 screen matrix ----------------
// grid (64,64), 256 threads (4 waves, 2x2 wave grid), 128x128 tile, K=384.
// dh[i][j] = fp16( sq[j] - 2 * dot_bf16(x_i, x_j) )   (row-constant sq[i] omitted)
__global__ void __launch_bounds__(256) dist_gemm_kernel(
    const unsigned short* __restrict__ xb, const float* __restrict__ sq,
    __half* __restrict__ dh)
{
    __shared__ unsigned short Abuf[128 * 32];   // 8 KB
    __shared__ unsigned short Bbuf[128 * 32];   // 8 KB
    __shared__ __align__(16) __half Dt[128 * 132];  // 33 KB, stride 132 halves (66 dwords)

    const int tid = threadIdx.x;
    const int wave = tid >> 6;
    const int lane = tid & 63;
    const int rowbase = blockIdx.x * 128;
    const int colbase = blockIdx.y * 128;
    const int wr = (wave >> 1) * 64;
    const int wc = (wave & 1) * 64;
    const int m16 = lane & 15;
    const int kq = lane >> 4;

    const int er0 = tid >> 2;
    const int er1 = 64 + (tid >> 2);
    const int eko = tid & 3;

    f32x4 acc[4][4];
    #pragma unroll
    for (int a = 0; a < 4; ++a)
        #pragma unroll
        for (int b = 0; b < 4; ++b)
            acc[a][b] = (f32x4){0.f, 0.f, 0.f, 0.f};

    for (int kb = 0; kb < DDIM / 32; ++kb) {
        const int k0 = kb * 32;
        __syncthreads();
        __builtin_amdgcn_global_load_lds(
            (const __attribute__((address_space(1))) void*)(xb + (size_t)(rowbase + er0) * DDIM + k0 + eko * 8),
            (__attribute__((address_space(3))) void*)((char*)Abuf + (wave * 64) * 16),
            16, 0, 0);
        __builtin_amdgcn_global_load_lds(
            (const __attribute__((address_space(1))) void*)(xb + (size_t)(rowbase + er1) * DDIM + k0 + eko * 8),
            (__attribute__((address_space(3))) void*)((char*)Abuf + (256 + wave * 64) * 16),
            16, 0, 0);
        __builtin_amdgcn_global_load_lds(
            (const __attribute__((address_space(1))) void*)(xb + (size_t)(colbase + er0) * DDIM + k0 + eko * 8),
            (__attribute__((address_space(3))) void*)((char*)Bbuf + (wave * 64) * 16),
            16, 0, 0);
        __builtin_amdgcn_global_load_lds(
            (const __attribute__((address_space(1))) void*)(xb + (size_t)(colbase + er1) * DDIM + k0 + eko * 8),
            (__attribute__((address_space(3))) void*)((char*)Bbuf + (256 + wave * 64) * 16),
            16, 0, 0);
        __syncthreads();

        bf16x8 af[4], bfr[4];
        #pragma unroll
        for (int s = 0; s < 4; ++s) {
            af[s]  = *(const bf16x8*)&Abuf[(wr + s * 16 + m16) * 32 + kq * 8];
            bfr[s] = *(const bf16x8*)&Bbuf[(wc + s * 16 + m16) * 32 + kq * 8];
        }
        #pragma unroll
        for (int si = 0; si < 4; ++si)
            #pragma unroll
            for (int sj = 0; sj < 4; ++sj)
                acc[si][sj] = __builtin_amdgcn_mfma_f32_16x16x32_bf16(
                    af[si], bfr[sj], acc[si][sj], 0, 0, 0);
    }

    // epilogue: acc -> fp16 Dt (layout fix) -> coalesced global stores
    float sqc[4];
    #pragma unroll
    for (int sj = 0; sj < 4; ++sj) sqc[sj] = sq[colbase + wc + sj * 16 + m16];

    #pragma unroll
    for (int si = 0; si < 4; ++si)
        #pragma unroll
        for (int sj = 0; sj < 4; ++sj) {
            int r = wr + si * 16 + kq * 4;
            int c = wc + sj * 16 + m16;
            #pragma unroll
            for (int v = 0; v < 4; ++v)
                Dt[(r + v) * 132 + c] = __float2half(sqc[sj] - 2.0f * acc[si][sj][v]);
        }
    __syncthreads();

    // store pass: 8 iters, 4 rows x 16 chunks of 16B per wave-instr
    #pragma unroll
    for (int it = 0; it < 8; ++it) {
        int r = it * 16 + (tid >> 4);
        int ch = tid & 15;
        const __half* p = &Dt[r * 132 + ch * 8];
        union { uint2 q[2]; float4 f; } u;
        u.q[0] = *(const uint2*)p;
        u.q[1] = *(const uint2*)(p + 4);
        *(float4*)&dh[(size_t)(rowbase + r) * NROWS + colbase + ch * 8] = u.f;
    }
}

// ---------------- streaming per-row top-32 screen (1 wave / row) ----------------
__global__ void __launch_bounds__(256) select_kernel(
    const __half* __restrict__ dh, int* __restrict__ cand)
{
    int row = blockIdx.x * 4 + (threadIdx.x >> 6);
    int lane = threadIdx.x & 63;
    const __half* rp = dh + (size_t)row * NROWS;

    float dv[8]; int jv[8];
    #pragma unroll
    for (int t = 0; t < 8; ++t) { dv[t] = INFINITY; jv[t] = 0x7fffffff; }

    for (int step = 0; step < NROWS / 512; ++step) {
        int col0 = step * 512 + lane * 8;
        union { float4 f; __half h[8]; } u;
        u.f = *(const float4*)(rp + col0);
        float e[8];
        #pragma unroll
        for (int t = 0; t < 8; ++t) e[t] = __half2float(u.h[t]);
        float m = fminf(fminf(fminf(e[0], e[1]), fminf(e[2], e[3])),
                        fminf(fminf(e[4], e[5]), fminf(e[6], e[7])));
        if (m < dv[7]) {
            #pragma unroll
            for (int t = 0; t < 8; ++t) {
                float d = e[t];
                if (d < dv[7]) {
                    dv[7] = d; jv[7] = col0 + t;
                    #pragma unroll
                    for (int q = 7; q > 0; --q) {
                        if (dv[q] < dv[q-1]) {
                            float td = dv[q]; dv[q] = dv[q-1]; dv[q-1] = td;
                            int tj = jv[q]; jv[q] = jv[q-1]; jv[q-1] = tj;
                        }
                    }
                }
            }
        }
    }

    // wave-wide extraction of top-32 (approx; exact rescore follows)
    float cur = dv[0];
    for (int t = 0; t < 32; ++t) {
        float m = cur;
        #pragma unroll
        for (int off = 32; off > 0; off >>= 1) m = fminf(m, __shfl_xor(m, off));
        unsigned long long b = __ballot(cur == m);
        int first = (int)(__ffsll((unsigned long long)b) - 1);
        if (lane == first) {
            cand[(size_t)row * 32 + t] = jv[0];
            #pragma unroll
            for (int q = 0; q < 7; ++q) { dv[q] = dv[q+1]; jv[q] = jv[q+1]; }
            dv[7] = INFINITY;
            cur = dv[0];
        }
    }
}

// ---------------- exact fp32 rescore of 32 candidates -> final sorted top-16 ----------------
__global__ void __launch_bounds__(256) rescore_kernel(
    const float* __restrict__ x, const float* __restrict__ sq,
    const int* __restrict__ cand, int* __restrict__ idxOut)
{
    int row = blockIdx.x * 4 + (threadIdx.x >> 6);
    int lane = threadIdx.x & 63;
    float xr[6];
    #pragma unroll
    for (int q = 0; q < 6; ++q) xr[q] = x[(size_t)row * DDIM + lane + 64 * q];
    int myj = cand[(size_t)row * 32 + (lane & 31)];
    float sqrow = sq[row];
    float myd = 0.f;
    for (int c = 0; c < 32; ++c) {
        int j = __shfl(myj, c);
        const float* xc = x + (size_t)j * DDIM;
        float p = 0.f;
        #pragma unroll
        for (int q = 0; q < 6; ++q) p = fmaf(xr[q], xc[lane + 64 * q], p);
        #pragma unroll
        for (int off = 32; off > 0; off >>= 1) p += __shfl_xor(p, off);
        float d = sqrow + sq[j] - 2.f * p;
        if (lane == c) myd = d;
    }
    int rank = 0;
    for (int t = 0; t < 32; ++t) {
        float dt = __shfl(myd, t); int jt = __shfl(myj, t);
        if (dj_better(dt, jt, myd, myj)) ++rank;
    }
    if (lane < 32 && rank < 16) idxOut[(size_t)row * 16 + rank] = myj;
}

// ---------------- gather-mean: agg[row] = mean of first k neighbors' h ----------------
__global__ void __launch_bounds__(256) aggregate_kernel(
    const float* __restrict__ h, const int* __restrict__ idx, const int* __restrict__ kk,
    float* __restrict__ agg)
{
    int row = blockIdx.x, tid = threadIdx.x;
    __shared__ int sidx[16];
    __shared__ int sk;
    if (tid < 16) sidx[tid] = idx[(size_t)row * 16 + tid];
    if (tid == 0) sk = kk[row];
    __syncthreads();
    int k = sk;
    float acc = 0.f;
    for (int t = 0; t < k; ++t) acc += h[(size_t)sidx[t] * HDIM + tid];
    agg[(size_t)row * HDIM + tid] = acc / (float)k;
}

// ---------------- LayerNorm(h + r) * g + b, then @ W_fc + b_fc ----------------
__global__ void __launch_bounds__(256) ln_fc_kernel(
    const float* __restrict__ h, const float* __restrict__ r,
    const float* __restrict__ g, const float* __restrict__ bb,
    const float* __restrict__ W_fc, const float* __restrict__ b_fc,
    float* __restrict__ out)
{
    int row = blockIdx.x, tid = threadIdx.x;
    int wave = tid >> 6, lane = tid & 63;
    float z = h[(size_t)row * HDIM + tid] + r[(size_t)row * HDIM + tid];
    float s = z, s2 = z * z;
    #pragma unroll
    for (int off = 32; off > 0; off >>= 1) { s += __shfl_xor(s, off); s2 += __shfl_xor(s2, off); }
    __shared__ float red[8];
    __shared__ float smv[2];
    if (lane == 0) { red[wave] = s; red[4 + wave] = s2; }
    __syncthreads();
    if (tid == 0) {
        float ts = red[0] + red[1] + red[2] + red[3];
        float t2 = red[4] + red[5] + red[6] + red[7];
        float mu = ts / 256.f;
        float var = t2 / 256.f - mu * mu;
        smv[0] = mu; smv[1] = rsqrtf(var + LN_EPS);
    }
    __syncthreads();
    float zn = (z - smv[0]) * smv[1];
    float val = zn * g[tid] + bb[tid];
    float p[6];
    #pragma unroll
    for (int c = 0; c < 6; ++c) p[c] = val * W_fc[tid * 6 + c];
    #pragma unroll
    for (int c = 0; c < 6; ++c)
        #pragma unroll
        for (int off = 32; off > 0; off >>= 1) p[c] += __shfl_xor(p[c], off);
    __shared__ float pr[4][6];
    if (lane == 0) {
        #pragma unroll
        for (int c = 0; c < 6; ++c) pr[wave][c] = p[c];
    }
    __syncthreads();
    if (tid < 6)
        out[(size_t)row * CDIM + tid] = pr[0][tid] + pr[1][tid] + pr[2][tid] + pr[3][tid] + b_fc[tid];
}

extern "C" void kernel_launch(void* const* d_in, const int* in_sizes, int n_in,
                              void* d_out, int out_size, void* d_ws, size_t ws_size,
                              hipStream_t stream) {
    const float* x      = (const float*)d_in[0];
    const float* W_proj = (const float*)d_in[1];
    const float* b_proj = (const float*)d_in[2];
    const float* W_tau  = (const float*)d_in[3];
    const float* b_tau  = (const float*)d_in[4];
    const float* W_res  = (const float*)d_in[5];
    const float* b_res  = (const float*)d_in[6];
    const float* ln_g   = (const float*)d_in[7];
    const float* ln_b   = (const float*)d_in[8];
    const float* W_fc   = (const float*)d_in[9];
    const float* b_fc   = (const float*)d_in[10];
    float* out = (float*)d_out;

    char* ws = (char*)d_ws;
    float* sq   = (float*)ws;                        ws += (size_t)NROWS * 4;
    int*   kk   = (int*)ws;                          ws += (size_t)NROWS * 4;
    float* h    = (float*)ws;                        ws += (size_t)NROWS * HDIM * 4;
    float* agg  = (float*)ws;                        ws += (size_t)NROWS * HDIM * 4;
    float* r    = (float*)ws;                        ws += (size_t)NROWS * HDIM * 4;
    int*   idx  = (int*)ws;                          ws += (size_t)NROWS * 16 * 4;
    int*   cand = (int*)ws;                          ws += (size_t)NROWS * 32 * 4;
    unsigned short* xb = (unsigned short*)ws;        ws += (size_t)NROWS * DDIM * 2;
    ws = (char*)(((size_t)ws + 255) & ~(size_t)255);
    __half* dh  = (__half*)ws;                       ws += (size_t)NROWS * NROWS * 2;

    tobf16_kernel<<<NROWS * DDIM / 256, 256, 0, stream>>>(x, xb);
    precompute_kernel<<<NROWS / 4, 256, 0, stream>>>(x, W_tau, b_tau, sq, kk);
    gemm_bias_relu_kernel<<<dim3(NROWS / 64, HDIM / 64), 256, 0, stream>>>(
        x, W_proj, b_proj, h, HDIM, DDIM);
    dist_gemm_kernel<<<dim3(NROWS / 128, NROWS / 128), 256, 0, stream>>>(xb, sq, dh);
    select_kernel<<<NROWS / 4, 256, 0, stream>>>(dh, cand);
    rescore_kernel<<<NROWS / 4, 256, 0, stream>>>(x, sq, cand, idx);
    aggregate_kernel<<<NROWS, 256, 0, stream>>>(h, idx, kk, agg);
    gemm_bias_relu_kernel<<<dim3(NROWS / 64, HDIM / 64), 256, 0, stream>>>(
        agg, W_res, b_res, r, HDIM, HDIM);
    ln_fc_kernel<<<NROWS, 256, 0, stream>>>(h, r, ln_g, ln_b, W_fc, b_fc, out);
}